// Round 8
// baseline (314.221 us; speedup 1.0000x reference)
//
#include <hip/hip_runtime.h>

// Problem: B=8, C=64, W=256, H=256, fp32.
// out[b,c,w,h] = sig(Wc@mean_wh(x)+bc)[b,c] * sig(Ww@mean_ch(x)+bw)[b,w] * sig(Wh@mean_cw(x)+bh)[b,h]
// Memory-bound: read 134MB + write 134MB.
// R1: no atomics/reduces inside the load loop (in-order vmcnt).
// R2/R3: atomics+memset == partials+reduce (58.5us).
// R4: thread-per-output gate dots = uncoalesced weight reads. ALWAYS wave-per-output.
// R6: persistent fusion + SPIN barriers = 334us disaster. Never spin.
// R7: pool 512thr + nt loads -> 57.25us. Pool ~5.4TB/s (near ceiling), out at
//     write ceiling; remaining slack = dispatch boundaries + atomic tail.
// R8: ticket-tail fusion (wait-free): pool -> 8-replica atomics (1/8 contention)
//     -> threadfence -> ticket; LAST block per b computes gates in-kernel
//     (coalesced wave-per-output). 3 dispatches: memset, pool+gates, out.

#define NB 8
#define NC 64
#define NW 256
#define NH 256

typedef float f4v __attribute__((ext_vector_type(4)));

// d_out-head scratch (floats; memset each call; overwritten by out_kernel):
//   [0,16)       tickets (8 used, as unsigned)
//   [16,36880)   8 replicas of {sum_c[512], sum_w[2048], sum_h[2048]}
#define REP_BASE 16
#define REP_SZ   4608
#define REP_SUMW 512
#define REP_SUMH 2560
// ws floats: gate_c [0,512)  gate_w [512,2560)  gate_h [2560,4608)

__device__ __forceinline__ float aload(const float* p) {
    return __hip_atomic_load(p, __ATOMIC_RELAXED, __HIP_MEMORY_SCOPE_AGENT);
}

__global__ __launch_bounds__(512) void pool_kernel(
        const float* __restrict__ x, float* __restrict__ ps,
        const float* __restrict__ Wc, const float* __restrict__ bc_,
        const float* __restrict__ Ww, const float* __restrict__ bw_,
        const float* __restrict__ Wh, const float* __restrict__ bh_,
        float* __restrict__ ws) {
    int k    = blockIdx.x;         // 0..1023
    int bc   = k >> 1;             // b*64 + c
    int half = k & 1;              // 128-row half
    int b    = bc >> 6;
    int tid  = threadIdx.x;        // 0..511
    int wv   = tid >> 6;           // wave 0..7
    int lane = tid & 63;
    int wbase = half * 128;

    float* rep = ps + REP_BASE + (size_t)(k & 7) * REP_SZ;   // this block's replica

    const f4v* xr = (const f4v*)x + (size_t)bc * (NW * (NH / 4));

    __shared__ float rowsum[8][16];   // [wave][j] : row wbase + wv + 8j
    __shared__ float cols[8][NH];
    __shared__ float wpart[4];
    __shared__ float s_c[64], s_w[256], s_h[256];
    __shared__ unsigned last_flag;

    f4v col = {0.f, 0.f, 0.f, 0.f};
    for (int jb = 0; jb < 16; jb += 8) {
        f4v v[8];
        #pragma unroll
        for (int i = 0; i < 8; ++i)
            v[i] = __builtin_nontemporal_load(
                xr + (size_t)(wbase + wv + 8 * (jb + i)) * (NH / 4) + lane);
        float rs[8];
        #pragma unroll
        for (int i = 0; i < 8; ++i) {
            col += v[i];
            rs[i] = (v[i][0] + v[i][1]) + (v[i][2] + v[i][3]);
        }
        #pragma unroll
        for (int off = 32; off; off >>= 1) {
            #pragma unroll
            for (int i = 0; i < 8; ++i) rs[i] += __shfl_xor(rs[i], off);
        }
        #pragma unroll
        for (int i = 0; i < 8; ++i)
            if (lane == i) rowsum[wv][jb + i] = rs[i];
    }

    cols[wv][lane * 4 + 0] = col[0];
    cols[wv][lane * 4 + 1] = col[1];
    cols[wv][lane * 4 + 2] = col[2];
    cols[wv][lane * 4 + 3] = col[3];
    __syncthreads();

    if (tid < 256) {
        float cv = 0.f;
        #pragma unroll
        for (int w8 = 0; w8 < 8; ++w8) cv += cols[w8][tid];
        atomicAdd(&rep[REP_SUMH + b * NH + tid], cv);
        float t = cv;
        #pragma unroll
        for (int off = 32; off; off >>= 1) t += __shfl_xor(t, off);
        if (lane == 0) wpart[wv] = t;
    }
    if (tid < 128)
        atomicAdd(&rep[REP_SUMW + b * NW + wbase + tid], rowsum[tid & 7][tid >> 3]);
    __syncthreads();
    if (tid == 0)
        atomicAdd(&rep[bc], (wpart[0] + wpart[1]) + (wpart[2] + wpart[3]));

    // ---- ticket: last of the 128 blocks for this b computes the gates ----
    __threadfence();                 // drain this block's atomics
    __syncthreads();
    if (tid == 0) {
        unsigned old = atomicAdd((unsigned*)ps + b, 1u);
        last_flag = (old == 127u);
    }
    __syncthreads();
    if (!last_flag) return;
    __threadfence();                 // acquire: all 128 blocks' atomics visible

    // sum the 8 replicas into LDS
    if (tid < 256) {
        float s = 0.f;
        #pragma unroll
        for (int r = 0; r < 8; ++r)
            s += aload(ps + REP_BASE + r * REP_SZ + REP_SUMH + b * 256 + tid);
        s_h[tid] = s;
    } else {
        int t = tid - 256;
        float s = 0.f;
        #pragma unroll
        for (int r = 0; r < 8; ++r)
            s += aload(ps + REP_BASE + r * REP_SZ + REP_SUMW + b * 256 + t);
        s_w[t] = s;
    }
    if (tid < 64) {
        float s = 0.f;
        #pragma unroll
        for (int r = 0; r < 8; ++r)
            s += aload(ps + REP_BASE + r * REP_SZ + b * 64 + tid);
        s_c[tid] = s;
    }
    __syncthreads();

    // 8 waves cover 576 gate outputs, wave-per-output (coalesced weight reads)
    float* gate_c = ws;
    float* gate_w = ws + 512;
    float* gate_h = ws + 2560;
    for (int id = wv; id < 576; id += 8) {
        float acc, bias;
        float* dst;
        if (id < 64) {                       // gate_c: dot-64
            acc = Wc[id * 64 + lane] * s_c[lane] * (1.f / 65536.f);
            bias = bc_[id];
            dst = &gate_c[b * 64 + id];
        } else if (id < 320) {               // gate_w: dot-256
            int o = id - 64;
            acc = 0.f;
            #pragma unroll
            for (int m = 0; m < 4; ++m)
                acc += Ww[o * 256 + lane + 64 * m] * s_w[lane + 64 * m];
            acc *= (1.f / 16384.f);
            bias = bw_[o];
            dst = &gate_w[b * 256 + o];
        } else {                             // gate_h: dot-256
            int o = id - 320;
            acc = 0.f;
            #pragma unroll
            for (int m = 0; m < 4; ++m)
                acc += Wh[o * 256 + lane + 64 * m] * s_h[lane + 64 * m];
            acc *= (1.f / 16384.f);
            bias = bh_[o];
            dst = &gate_h[b * 256 + o];
        }
        #pragma unroll
        for (int off = 32; off; off >>= 1) acc += __shfl_xor(acc, off);
        if (lane == 0) *dst = 1.f / (1.f + expf(-(acc + bias)));
    }
}

__global__ __launch_bounds__(256) void out_kernel(const float* __restrict__ ws,
                                                  float* __restrict__ out) {
    const float* gate_c = ws;
    const float* gate_w = ws + 512;
    const float4* gate_h4 = (const float4*)(ws + 2560);

    const size_t N4 = (size_t)NB * NC * NW * (NH / 4);  // 8388608
    size_t stride = (size_t)gridDim.x * blockDim.x;
    for (size_t i = (size_t)blockIdx.x * blockDim.x + threadIdx.x; i < N4; i += stride) {
        int h4 = (int)(i & 63);          // H/4 = 64
        size_t row = i >> 6;
        int w = (int)(row & 255);        // W = 256
        size_t bcr = row >> 8;
        int c = (int)(bcr & 63);         // C = 64
        int b = (int)(bcr >> 6);
        float g = gate_c[b * 64 + c] * gate_w[b * 256 + w];
        float4 gh = gate_h4[b * 64 + h4];
        f4v val = {g * gh.x, g * gh.y, g * gh.z, g * gh.w};
        __builtin_nontemporal_store(val, (f4v*)(out + 4 * i));
    }
}

extern "C" void kernel_launch(void* const* d_in, const int* in_sizes, int n_in,
                              void* d_out, int out_size, void* d_ws, size_t ws_size,
                              hipStream_t stream) {
    const float* x   = (const float*)d_in[0];
    const float* Wc  = (const float*)d_in[1];
    const float* bc_ = (const float*)d_in[2];
    const float* Ww  = (const float*)d_in[3];
    const float* bw_ = (const float*)d_in[4];
    const float* Wh  = (const float*)d_in[5];
    const float* bh_ = (const float*)d_in[6];
    float* ws = (float*)d_ws;
    float* ps = (float*)d_out;   // d_out head = tickets + replica accumulators

    // zero tickets + replicas (16 + 8*4608 floats); overwritten by out_kernel
    hipMemsetAsync(ps, 0, (REP_BASE + 8 * REP_SZ) * sizeof(float), stream);

    pool_kernel<<<1024, 512, 0, stream>>>(x, ps, Wc, bc_, Ww, bw_, Wh, bh_, ws);
    out_kernel<<<2048, 256, 0, stream>>>(ws, (float*)d_out);
}

// Round 9
// 61.371 us; speedup vs baseline: 5.1201x; 5.1201x over previous
//
#include <hip/hip_runtime.h>

// Problem: B=8, C=64, W=256, H=256, fp32.
// out[b,c,w,h] = sig(Wc@mean_wh(x)+bc)[b,c] * sig(Ww@mean_ch(x)+bw)[b,w] * sig(Wh@mean_cw(x)+bh)[b,h]
// Memory-bound: read 134MB + write 134MB.
// R1: no atomics/reduces inside the load loop (in-order vmcnt).
// R2/R3: atomics+memset == partials+reduce (58.5us).
// R4: few-block consumers of grid-wide dirty partials = cross-XCD tail.
// R6/R8: in-kernel cross-block handoff needs __threadfence (device-scope L2
//        writeback) -> ~300us at 1024 blocks. Dispatch boundary IS the fence.
//        4-dispatch structure is FINAL.
// R7: best = 57.25us. pool ~28us but FETCH=65MB (half L3-hit) -> concurrency-
//     limited, not BW-limited. out at write ceiling (~7TB/s fill-proven).
// R9: pool: 2048 blocks x 256 thr (8 blk/CU), interleaved row mapping (R2's,
//     beat R5's contiguous), 8-deep batches, plain loads, R2 atomic counts.

#define NB 8
#define NC 64
#define NW 256
#define NH 256

typedef float f4v __attribute__((ext_vector_type(4)));

// ws float layout:
// [0,512)      sum_c   [512,2560) sum_w   [2560,4608) sum_h   (memset each call)
// [4608,5120)  gate_c  [5120,7168) gate_w [7168,9216) gate_h

__global__ __launch_bounds__(256) void pool_kernel(const float* __restrict__ x,
                                                   float* __restrict__ ws) {
    float* sum_c = ws;
    float* sum_w = ws + 512;
    float* sum_h = ws + 2560;

    int k    = blockIdx.x;         // 0..2047
    int bc   = k >> 2;             // b*64 + c
    int q    = k & 3;              // quarter: rows [q*64, q*64+64)
    int b    = bc >> 6;
    int tid  = threadIdx.x;        // 0..255
    int wv   = tid >> 6;           // wave 0..3
    int lane = tid & 63;
    int wbase = q * 64;

    const f4v* xr = (const f4v*)x + (size_t)bc * (NW * (NH / 4));

    __shared__ float rowsum[4][16];   // [wave][j] : row wbase + wv + 4j
    __shared__ float cols[4][NH];
    __shared__ float wpart[4];

    f4v col = {0.f, 0.f, 0.f, 0.f};
    // wave wv owns rows wbase + wv + 4j, j=0..15 (interleaved); 8-deep batches.
    for (int jb = 0; jb < 16; jb += 8) {
        f4v v[8];
        #pragma unroll
        for (int i = 0; i < 8; ++i)
            v[i] = xr[(size_t)(wbase + wv + 4 * (jb + i)) * (NH / 4) + lane];
        float rs[8];
        #pragma unroll
        for (int i = 0; i < 8; ++i) {
            col += v[i];
            rs[i] = (v[i][0] + v[i][1]) + (v[i][2] + v[i][3]);
        }
        #pragma unroll
        for (int off = 32; off; off >>= 1) {
            #pragma unroll
            for (int i = 0; i < 8; ++i) rs[i] += __shfl_xor(rs[i], off);
        }
        #pragma unroll
        for (int i = 0; i < 8; ++i)
            if (lane == i) rowsum[wv][jb + i] = rs[i];
    }

    cols[wv][lane * 4 + 0] = col[0];
    cols[wv][lane * 4 + 1] = col[1];
    cols[wv][lane * 4 + 2] = col[2];
    cols[wv][lane * 4 + 3] = col[3];
    __syncthreads();

    // h-partials: thread t owns column h=t; coalesced atomics
    float cv = cols[0][tid] + cols[1][tid] + cols[2][tid] + cols[3][tid];
    atomicAdd(&sum_h[b * NH + tid], cv);

    // row sums: local row r=tid (0..63): wave r&3, slot r>>2
    if (tid < 64)
        atomicAdd(&sum_w[b * NW + wbase + tid], rowsum[tid & 3][tid >> 2]);

    // block total -> sum_c
    float t = cv;
    #pragma unroll
    for (int off = 32; off; off >>= 1) t += __shfl_xor(t, off);
    if (lane == 0) wpart[wv] = t;
    __syncthreads();
    if (tid == 0)
        atomicAdd(&sum_c[bc], (wpart[0] + wpart[1]) + (wpart[2] + wpart[3]));
}

__global__ __launch_bounds__(256) void gates_kernel(const float* __restrict__ Wc, const float* __restrict__ bc_,
                                                    const float* __restrict__ Ww, const float* __restrict__ bw_,
                                                    const float* __restrict__ Wh, const float* __restrict__ bh_,
                                                    float* __restrict__ ws) {
    const float* sum_c = ws;
    const float* sum_w = ws + 512;
    const float* sum_h = ws + 2560;
    float* gate_c = ws + 4608;
    float* gate_w = ws + 5120;
    float* gate_h = ws + 7168;

    int j = blockIdx.x * 4 + (threadIdx.x >> 6);  // global wave id, 0..4607
    int lane = threadIdx.x & 63;

    float acc = 0.f, bias;
    float* dst;
    if (j < 512) {                                 // c-gate: dot length 64
        int b = j >> 6, o = j & 63;
        acc = Wc[o * 64 + lane] * sum_c[b * 64 + lane] * (1.f / 65536.f);
        bias = bc_[o];
        dst = &gate_c[j];
    } else if (j < 2560) {                         // w-gate: dot length 256
        int j2 = j - 512;
        int b = j2 >> 8, o = j2 & 255;
        const float* wr = Ww + o * 256;
        const float* sr = sum_w + b * 256;
        #pragma unroll
        for (int m = 0; m < 4; ++m) acc += wr[lane + 64 * m] * sr[lane + 64 * m];
        acc *= (1.f / 16384.f);
        bias = bw_[o];
        dst = &gate_w[j2];
    } else {                                       // h-gate: dot length 256
        int j2 = j - 2560;
        int b = j2 >> 8, o = j2 & 255;
        const float* wr = Wh + o * 256;
        const float* sr = sum_h + b * 256;
        #pragma unroll
        for (int m = 0; m < 4; ++m) acc += wr[lane + 64 * m] * sr[lane + 64 * m];
        acc *= (1.f / 16384.f);
        bias = bh_[o];
        dst = &gate_h[j2];
    }
    #pragma unroll
    for (int off = 32; off; off >>= 1) acc += __shfl_xor(acc, off);
    if (lane == 0) *dst = 1.f / (1.f + expf(-(acc + bias)));
}

__global__ __launch_bounds__(256) void out_kernel(const float* __restrict__ ws,
                                                  float* __restrict__ out) {
    const float* gate_c = ws + 4608;
    const float* gate_w = ws + 5120;
    const float4* gate_h4 = (const float4*)(ws + 7168);

    const size_t N4 = (size_t)NB * NC * NW * (NH / 4);  // 8388608
    size_t stride = (size_t)gridDim.x * blockDim.x;
    for (size_t i = (size_t)blockIdx.x * blockDim.x + threadIdx.x; i < N4; i += stride) {
        int h4 = (int)(i & 63);          // H/4 = 64
        size_t row = i >> 6;
        int w = (int)(row & 255);        // W = 256
        size_t bcr = row >> 8;
        int c = (int)(bcr & 63);         // C = 64
        int b = (int)(bcr >> 6);
        float g = gate_c[b * 64 + c] * gate_w[b * 256 + w];
        float4 gh = gate_h4[b * 64 + h4];
        f4v val = {g * gh.x, g * gh.y, g * gh.z, g * gh.w};
        __builtin_nontemporal_store(val, (f4v*)(out + 4 * i));
    }
}

extern "C" void kernel_launch(void* const* d_in, const int* in_sizes, int n_in,
                              void* d_out, int out_size, void* d_ws, size_t ws_size,
                              hipStream_t stream) {
    const float* x   = (const float*)d_in[0];
    const float* Wc  = (const float*)d_in[1];
    const float* bc_ = (const float*)d_in[2];
    const float* Ww  = (const float*)d_in[3];
    const float* bw_ = (const float*)d_in[4];
    const float* Wh  = (const float*)d_in[5];
    const float* bh_ = (const float*)d_in[6];
    float* ws = (float*)d_ws;

    // zero the atomic accumulators (sum_c, sum_w, sum_h)
    hipMemsetAsync(ws, 0, 4608 * sizeof(float), stream);

    pool_kernel<<<2048, 256, 0, stream>>>(x, ws);
    gates_kernel<<<4608 / 4, 256, 0, stream>>>(Wc, bc_, Ww, bw_, Wh, bh_, ws);
    out_kernel<<<2048, 256, 0, stream>>>(ws, (float*)d_out);
}

// Round 10
// 57.742 us; speedup vs baseline: 5.4418x; 1.0628x over previous
//
#include <hip/hip_runtime.h>

// Problem: B=8, C=64, W=256, H=256, fp32.
// out[b,c,w,h] = sig(Wc@mean_wh(x)+bc)[b,c] * sig(Ww@mean_ch(x)+bw)[b,w] * sig(Wh@mean_cw(x)+bh)[b,h]
// Memory-bound: read 134MB + write 134MB.
// R1: no atomics/reduces inside the load loop (in-order vmcnt).
// R2/R3: atomics+memset == partials+reduce (58.5us).
// R4: few-block consumers of grid-wide dirty partials = cross-XCD tail.
// R6/R8: in-kernel cross-block handoff needs __threadfence (device-scope L2
//        writeback) -> ~300us at 1024 blocks. Dispatch boundary IS the fence.
//        4-dispatch structure is FINAL.
// R7: BEST = 57.25us: pool 1024 blocks x 512 thr, nt loads, 8-deep batches.
// R9: 2048x256 + plain loads + doubled atomics = 61.4us. REVERTED.
// R10: byte-identical restore of R7 (measured optimum).

#define NB 8
#define NC 64
#define NW 256
#define NH 256

typedef float f4v __attribute__((ext_vector_type(4)));

// ws float layout:
// [0,512)      sum_c   [512,2560) sum_w   [2560,4608) sum_h   (memset each call)
// [4608,5120)  gate_c  [5120,7168) gate_w [7168,9216) gate_h

__global__ __launch_bounds__(512) void pool_kernel(const float* __restrict__ x,
                                                   float* __restrict__ ws) {
    float* sum_c = ws;
    float* sum_w = ws + 512;
    float* sum_h = ws + 2560;

    int k    = blockIdx.x;         // 0..1023
    int bc   = k >> 1;             // b*64 + c
    int half = k & 1;              // 128-row half
    int b    = bc >> 6;
    int tid  = threadIdx.x;        // 0..511
    int wv   = tid >> 6;           // wave 0..7
    int lane = tid & 63;
    int wbase = half * 128;

    const f4v* xr = (const f4v*)x + (size_t)bc * (NW * (NH / 4));

    __shared__ float rowsum[8][16];   // [wave][j] : row wbase + wv + 8j
    __shared__ float cols[8][NH];     // per-wave column partials
    __shared__ float wpart[4];

    f4v col = {0.f, 0.f, 0.f, 0.f};
    // wave wv owns rows wbase + wv + 8j, j=0..15; two batches of 8 in flight.
    for (int jb = 0; jb < 16; jb += 8) {
        f4v v[8];
        #pragma unroll
        for (int i = 0; i < 8; ++i)
            v[i] = __builtin_nontemporal_load(
                xr + (size_t)(wbase + wv + 8 * (jb + i)) * (NH / 4) + lane);
        float rs[8];
        #pragma unroll
        for (int i = 0; i < 8; ++i) {
            col += v[i];
            rs[i] = (v[i][0] + v[i][1]) + (v[i][2] + v[i][3]);
        }
        #pragma unroll
        for (int off = 32; off; off >>= 1) {
            #pragma unroll
            for (int i = 0; i < 8; ++i) rs[i] += __shfl_xor(rs[i], off);
        }
        #pragma unroll
        for (int i = 0; i < 8; ++i)
            if (lane == i) rowsum[wv][jb + i] = rs[i];
    }

    cols[wv][lane * 4 + 0] = col[0];
    cols[wv][lane * 4 + 1] = col[1];
    cols[wv][lane * 4 + 2] = col[2];
    cols[wv][lane * 4 + 3] = col[3];
    __syncthreads();

    // threads 0..255: column h=tid; one coalesced atomic per column
    if (tid < 256) {
        float cv = 0.f;
        #pragma unroll
        for (int w8 = 0; w8 < 8; ++w8) cv += cols[w8][tid];
        atomicAdd(&sum_h[b * NH + tid], cv);

        // block total -> sum_c (waves 0..3 of the cv values)
        float t = cv;
        #pragma unroll
        for (int off = 32; off; off >>= 1) t += __shfl_xor(t, off);
        if (lane == 0) wpart[wv] = t;
    }
    // threads 0..127: row r=tid of this half -> wave r&7, slot r>>3
    if (tid < 128)
        atomicAdd(&sum_w[b * NW + wbase + tid], rowsum[tid & 7][tid >> 3]);
    __syncthreads();
    if (tid == 0)
        atomicAdd(&sum_c[bc], (wpart[0] + wpart[1]) + (wpart[2] + wpart[3]));
}

__global__ __launch_bounds__(256) void gates_kernel(const float* __restrict__ Wc, const float* __restrict__ bc_,
                                                    const float* __restrict__ Ww, const float* __restrict__ bw_,
                                                    const float* __restrict__ Wh, const float* __restrict__ bh_,
                                                    float* __restrict__ ws) {
    const float* sum_c = ws;
    const float* sum_w = ws + 512;
    const float* sum_h = ws + 2560;
    float* gate_c = ws + 4608;
    float* gate_w = ws + 5120;
    float* gate_h = ws + 7168;

    int j = blockIdx.x * 4 + (threadIdx.x >> 6);  // global wave id, 0..4607
    int lane = threadIdx.x & 63;

    float acc = 0.f, bias;
    float* dst;
    if (j < 512) {                                 // c-gate: dot length 64
        int b = j >> 6, o = j & 63;
        acc = Wc[o * 64 + lane] * sum_c[b * 64 + lane] * (1.f / 65536.f);
        bias = bc_[o];
        dst = &gate_c[j];
    } else if (j < 2560) {                         // w-gate: dot length 256
        int j2 = j - 512;
        int b = j2 >> 8, o = j2 & 255;
        const float* wr = Ww + o * 256;
        const float* sr = sum_w + b * 256;
        #pragma unroll
        for (int m = 0; m < 4; ++m) acc += wr[lane + 64 * m] * sr[lane + 64 * m];
        acc *= (1.f / 16384.f);
        bias = bw_[o];
        dst = &gate_w[j2];
    } else {                                       // h-gate: dot length 256
        int j2 = j - 2560;
        int b = j2 >> 8, o = j2 & 255;
        const float* wr = Wh + o * 256;
        const float* sr = sum_h + b * 256;
        #pragma unroll
        for (int m = 0; m < 4; ++m) acc += wr[lane + 64 * m] * sr[lane + 64 * m];
        acc *= (1.f / 16384.f);
        bias = bh_[o];
        dst = &gate_h[j2];
    }
    #pragma unroll
    for (int off = 32; off; off >>= 1) acc += __shfl_xor(acc, off);
    if (lane == 0) *dst = 1.f / (1.f + expf(-(acc + bias)));
}

__global__ __launch_bounds__(256) void out_kernel(const float* __restrict__ ws,
                                                  float* __restrict__ out) {
    const float* gate_c = ws + 4608;
    const float* gate_w = ws + 5120;
    const float4* gate_h4 = (const float4*)(ws + 7168);

    const size_t N4 = (size_t)NB * NC * NW * (NH / 4);  // 8388608
    size_t stride = (size_t)gridDim.x * blockDim.x;
    for (size_t i = (size_t)blockIdx.x * blockDim.x + threadIdx.x; i < N4; i += stride) {
        int h4 = (int)(i & 63);          // H/4 = 64
        size_t row = i >> 6;
        int w = (int)(row & 255);        // W = 256
        size_t bcr = row >> 8;
        int c = (int)(bcr & 63);         // C = 64
        int b = (int)(bcr >> 6);
        float g = gate_c[b * 64 + c] * gate_w[b * 256 + w];
        float4 gh = gate_h4[b * 64 + h4];
        f4v val = {g * gh.x, g * gh.y, g * gh.z, g * gh.w};
        __builtin_nontemporal_store(val, (f4v*)(out + 4 * i));
    }
}

extern "C" void kernel_launch(void* const* d_in, const int* in_sizes, int n_in,
                              void* d_out, int out_size, void* d_ws, size_t ws_size,
                              hipStream_t stream) {
    const float* x   = (const float*)d_in[0];
    const float* Wc  = (const float*)d_in[1];
    const float* bc_ = (const float*)d_in[2];
    const float* Ww  = (const float*)d_in[3];
    const float* bw_ = (const float*)d_in[4];
    const float* Wh  = (const float*)d_in[5];
    const float* bh_ = (const float*)d_in[6];
    float* ws = (float*)d_ws;

    // zero the atomic accumulators (sum_c, sum_w, sum_h)
    hipMemsetAsync(ws, 0, 4608 * sizeof(float), stream);

    pool_kernel<<<1024, 512, 0, stream>>>(x, ws);
    gates_kernel<<<4608 / 4, 256, 0, stream>>>(Wc, bc_, Ww, bw_, Wh, bh_, ws);
    out_kernel<<<2048, 256, 0, stream>>>(ws, (float*)d_out);
}